// Round 16
// baseline (273.441 us; speedup 1.0000x reference)
//
#include <hip/hip_runtime.h>
#include <math.h>

#define BIGF 1e10f
#define EPSF 1e-5f

typedef _Float16 f16;
typedef f16 f16x8 __attribute__((ext_vector_type(8)));
typedef float f32x4 __attribute__((ext_vector_type(4)));

static __device__ __forceinline__ f16x8 mk8(uint a, uint b, uint c, uint d) {
    union { uint u[4]; f16x8 v; } t;
    t.u[0] = a; t.u[1] = b; t.u[2] = c; t.u[3] = d;
    return t.v;
}

// ---------------------------------------------------------------------------
// Prepack (unchanged, verified)
// ---------------------------------------------------------------------------
__global__ __launch_bounds__(256) void prepack(
    const float* __restrict__ c1w,
    const float* __restrict__ bn1g, const float* __restrict__ bn1b,
    const float* __restrict__ bn1m, const float* __restrict__ bn1v,
    const float* __restrict__ blkw,
    const float* __restrict__ blkg, const float* __restrict__ blkb,
    const float* __restrict__ blkm, const float* __restrict__ blkv,
    f16* __restrict__ wB, f16* __restrict__ wB1,
    float* __restrict__ b3, float* __restrict__ b1)
{
    int idx = blockIdx.x * 256 + threadIdx.x;
    if (idx < 147456) {                    // conv3 weight frags
        int pos = idx;
        int j    = pos & 7;
        int lane = (pos >> 3) & 63;
        int rest = pos >> 9;               // (((layer*9+tap)*4+nt)*2+kf)
        int kf   = rest & 1;
        int r2   = rest >> 1;
        int ntl  = r2 & 3;
        int r3   = r2 >> 2;
        int tap  = r3 % 9;
        int layer= r3 / 9;
        int ic = kf * 32 + (lane >> 4) * 8 + j;
        int oc = ntl * 16 + (lane & 15);
        float s = blkg[layer * 64 + oc] * rsqrtf(blkv[layer * 64 + oc] + EPSF);
        float wv = blkw[(((size_t)layer * 64 + oc) * 64 + ic) * 9 + tap] * s;
        f16 h = (f16)wv;
        f16 lo = (f16)(wv - (float)h);
        int low9 = pos & 511;
        wB[(size_t)rest * 1024 + low9]       = h;
        wB[(size_t)rest * 1024 + 512 + low9] = lo;
    }
    int q = idx - 147456;
    if (q >= 0 && q < 28672) {             // conv1 frags
        int j = q & 7, lane = (q >> 3) & 63, rest = q >> 9;  // ((kh*4+nt)*2+hl)
        int hl = rest & 1, nt = (rest >> 1) & 3, kh = rest >> 3;
        int oc = nt * 16 + (lane & 15), lgq = lane >> 4;
        float v = 0.f;
        if (lgq < 3 && j < 7) {
            float s = bn1g[oc] * rsqrtf(bn1v[oc] + EPSF);
            v = c1w[((oc * 3 + lgq) * 7 + kh) * 7 + j] * s;
        }
        f16 h = (f16)v;
        wB1[q] = hl ? (f16)(v - (float)h) : h;
    }
    int k = idx - 147456 - 28672;
    if (k >= 0 && k < 256) {
        float s = blkg[k] * rsqrtf(blkv[k] + EPSF);
        b3[k] = blkb[k] - blkm[k] * s;
    }
    int l = idx - 147456 - 28672 - 256;
    if (l >= 0 && l < 64) {
        float s = bn1g[l] * rsqrtf(bn1v[l] + EPSF);
        b1[l] = bn1b[l] - bn1m[l] * s;
    }
}

// ---------------------------------------------------------------------------
// conv1 7x7 s2 p3 + foldedBN + ReLU + maxpool via f16-split MFMA.
// (R9-verified, unchanged)
// ---------------------------------------------------------------------------
__global__ __launch_bounds__(256) void conv1_mfma(
    const float* __restrict__ x, const f16* __restrict__ wB1,
    const float* __restrict__ bias,
    f16* __restrict__ outh, f16* __restrict__ outl)
{
    __shared__ char lds[18720];
    const int g = blockIdx.x, b = blockIdx.y;
    const int tid = threadIdx.x;
    const int w = tid >> 6, l = tid & 63;
    const int l15 = l & 15, lg = l >> 4;

    for (int i = tid; i < 4680; i += 256) ((uint*)lds)[i] = 0u;
    __syncthreads();
    const int ir0 = 8 * g - 5;
    const float* xb = x + (size_t)b * 27648;
    for (int u = tid; u < 2205; u += 256) {
        int cu = 1 + (u % 49);
        int rr = (u / 49) % 15;
        int ic = u / 735;
        int ir = ir0 + rr;
        uint pk_h = 0u, pk_l = 0u;
        if ((unsigned)ir < 96u) {
            int c0i = 2 * cu - 3, c1i = 2 * cu - 2;
            const float* rowp = xb + ic * 9216 + ir * 96;
            float v0 = (c0i >= 0) ? rowp[c0i] : 0.f;
            float v1 = (c1i <= 95) ? rowp[c1i] : 0.f;
            f16 h0 = (f16)v0; f16 lo0 = (f16)(v0 - (float)h0);
            f16 h1 = (f16)v1; f16 lo1 = (f16)(v1 - (float)h1);
            union { f16 f[2]; uint u32; } ph, pl;
            ph.f[0] = h0;  ph.f[1] = h1;  pk_h = ph.u32;
            pl.f[0] = lo0; pl.f[1] = lo1; pk_l = pl.u32;
        }
        int off = ic * 3120 + rr * 208 + 4 * cu;
        *(uint*)(lds + off) = pk_h;
        *(uint*)(lds + 9360 + off) = pk_l;
    }
    __syncthreads();

    f32x4 acc[4][4];
#pragma unroll
    for (int k = 0; k < 4; ++k)
#pragma unroll
        for (int nt = 0; nt < 4; ++nt) acc[k][nt] = (f32x4){0.f, 0.f, 0.f, 0.f};

    const int icB = (lg >= 3 ? 0 : lg) * 3120;
    const char* hbase = lds + icB;
    const char* lbase = lds + 9360 + icB;
    const f16* wq = wB1 + (size_t)l * 8;

    int rowoff[4], aoff[4];
#pragma unroll
    for (int k = 0; k < 4; ++k) {
        int t = w + 4 * k;
        int tt = (t < 15) ? t : 0;
        rowoff[k] = tt / 3;
        aoff[k] = 4 * ((tt % 3) * 16 + l15);
    }

#pragma unroll 1
    for (int kh = 0; kh < 7; ++kh) {
        const f16* wk = wq + kh * 4096;
        f16x8 bq[4];
#pragma unroll
        for (int nt = 0; nt < 4; ++nt)
            bq[nt] = *(const f16x8*)(const void*)(wk + nt * 1024);
#pragma unroll
        for (int k = 0; k < 4; ++k) {
            if (w + 4 * k < 15) {
                int ro = (2 * rowoff[k] + kh) * 208 + aoff[k];
                const uint* ph = (const uint*)(hbase + ro);
                const uint* pl = (const uint*)(lbase + ro);
                f16x8 ah = mk8(ph[0], ph[1], ph[2], ph[3]);
                f16x8 al = mk8(pl[0], pl[1], pl[2], pl[3]);
#pragma unroll
                for (int nt = 0; nt < 4; ++nt) {
                    acc[k][nt] = __builtin_amdgcn_mfma_f32_16x16x32_f16(ah, bq[nt], acc[k][nt], 0, 0, 0);
                    acc[k][nt] = __builtin_amdgcn_mfma_f32_16x16x32_f16(al, bq[nt], acc[k][nt], 0, 0, 0);
                }
            }
        }
#pragma unroll
        for (int nt = 0; nt < 4; ++nt)
            bq[nt] = *(const f16x8*)(const void*)(wk + nt * 1024 + 512);
#pragma unroll
        for (int k = 0; k < 4; ++k) {
            if (w + 4 * k < 15) {
                int ro = (2 * rowoff[k] + kh) * 208 + aoff[k];
                const uint* ph = (const uint*)(hbase + ro);
                f16x8 ah = mk8(ph[0], ph[1], ph[2], ph[3]);
#pragma unroll
                for (int nt = 0; nt < 4; ++nt)
                    acc[k][nt] = __builtin_amdgcn_mfma_f32_16x16x32_f16(ah, bq[nt], acc[k][nt], 0, 0, 0);
            }
        }
    }

    __syncthreads();
    float* pbuf = (float*)(void*)lds;
#pragma unroll
    for (int og = 0; og < 4; ++og) {
        float bi = bias[og * 16 + l15];
#pragma unroll
        for (int k = 0; k < 4; ++k) {
            int t = w + 4 * k;
            if (t < 15) {
                int lr = t / 3;
                int c0 = (t % 3) * 16;
#pragma unroll
                for (int r = 0; r < 4; ++r) {
                    int col = c0 + lg * 4 + r;
                    pbuf[(lr * 48 + col) * 17 + l15] = fmaxf(acc[k][og][r] + bi, 0.f);
                }
            }
        }
        __syncthreads();
#pragma unroll
        for (int it = 0; it < 3; ++it) {
            int idx = tid + it * 256;
            int oc = idx & 15, p2 = idx >> 4;
            int pc2 = p2 % 24, pr2 = p2 / 24;
            float m = -INFINITY;
#pragma unroll
            for (int kr = 0; kr < 3; ++kr) {
                int lr = 2 * pr2 + kr;
                if (g == 0 && lr == 0) continue;
#pragma unroll
                for (int kc = 0; kc < 3; ++kc) {
                    int cc = 2 * pc2 - 1 + kc;
                    if ((unsigned)cc < 48u)
                        m = fmaxf(m, pbuf[(lr * 48 + cc) * 17 + oc]);
                }
            }
            f16 h = (f16)m;
            f16 lo = (f16)(m - (float)h);
            size_t off = (size_t)b * 36864 +
                         (size_t)((2 * g + pr2) * 24 + pc2) * 64 + og * 16 + oc;
            outh[off] = h;
            outl[off] = lo;
        }
        __syncthreads();
    }
}

// ---------------------------------------------------------------------------
// conv3x3 s1 p1 (64->64) + foldedBN (+res) + ReLU via f16-split MFMA, v2:
// 4-row blocks, grid (6,128) = 3 blocks/CU. (R15-verified)
// ---------------------------------------------------------------------------
template<int MODE, int OUTT>
__global__ __launch_bounds__(256) void conv3_mfma(
    const f16* __restrict__ inh, const f16* __restrict__ inl,
    const f16* __restrict__ wB,      // this layer's frag base (73728 halves)
    const float* __restrict__ bias,  // folded [64]
    const f16* __restrict__ resh, const f16* __restrict__ resl,
    f16* __restrict__ outh, f16* __restrict__ outl)
{
    __shared__ f16 lh[6 * 26 * 64];
    __shared__ f16 ll[6 * 26 * 64];
    const int r0 = blockIdx.x * 4;
    const int b  = blockIdx.y;
    const int tid = threadIdx.x;
    const int w = tid >> 6, l = tid & 63;
    const int l15 = l & 15, lg = l >> 4;

    if (tid < 192) {
        int arr = tid >= 96; int c2 = tid - arr * 96;
        int slot = c2 & 7; int pb = c2 >> 3;
        int lr = pb >> 1; int pc = (pb & 1) ? 25 : 0;
        int pix = lr * 26 + pc;
        int off = (pix * 128 + slot * 16) ^ ((pix & 7) << 4);
        *(uint4*)((arr ? (char*)ll : (char*)lh) + off) = make_uint4(0, 0, 0, 0);
    }
#pragma unroll
    for (int i = 0; i < 9; ++i) {
        int ch = tid + i * 256;
        int arr = ch >= 1152; int c2 = ch - arr * 1152;
        int slot = c2 & 7; int pix24 = c2 >> 3;
        int lr = pix24 / 24, pc = pix24 % 24;
        int ir = r0 - 1 + lr;
        uint4 v = make_uint4(0, 0, 0, 0);
        if ((unsigned)ir < 24u) {
            const f16* src = (arr ? inl : inh) +
                (((size_t)b * 576 + ir * 24 + pc) << 6) + slot * 8;
            v = *(const uint4*)(const void*)src;
        }
        int pix = lr * 26 + pc + 1;
        int off = (pix * 128 + slot * 16) ^ ((pix & 7) << 4);
        *(uint4*)((arr ? (char*)ll : (char*)lh) + off) = v;
    }

    int pr_[2], pc_[2];
#pragma unroll
    for (int mtl = 0; mtl < 2; ++mtl) {
        int t = w + 4 * mtl;
        int tt = (t < 6) ? t : 0;
        int lp = tt * 16 + l15;
        pr_[mtl] = lp / 24; pc_[mtl] = lp % 24;
    }

    f32x4 acc[2][4];
#pragma unroll
    for (int m = 0; m < 2; ++m)
#pragma unroll
        for (int n = 0; n < 4; ++n) acc[m][n] = (f32x4){0.f, 0.f, 0.f, 0.f};

    __syncthreads();

#pragma unroll 1
    for (int tap = 0; tap < 9; ++tap) {
        int dr = tap / 3, dc = tap % 3;
#pragma unroll
        for (int kf = 0; kf < 2; ++kf) {
            const f16* wb = wB + (size_t)tap * 8192 + (size_t)kf * 1024 + (size_t)l * 8;
            f16x8 bh[4], bl[4];
#pragma unroll
            for (int nt = 0; nt < 4; ++nt) {
                bh[nt] = *(const f16x8*)(const void*)(wb + nt * 2048);
                bl[nt] = *(const f16x8*)(const void*)(wb + nt * 2048 + 512);
            }
#pragma unroll
            for (int mtl = 0; mtl < 2; ++mtl) {
                if (mtl == 1 && w >= 2) continue;
                int pix = (pr_[mtl] + dr) * 26 + (pc_[mtl] + dc);
                int off = (pix * 128 + kf * 64 + lg * 16) ^ ((pix & 7) << 4);
                f16x8 ah = *(const f16x8*)((const char*)lh + off);
                f16x8 al = *(const f16x8*)((const char*)ll + off);
#pragma unroll
                for (int nt = 0; nt < 4; ++nt) {
                    acc[mtl][nt] = __builtin_amdgcn_mfma_f32_16x16x32_f16(ah, bh[nt], acc[mtl][nt], 0, 0, 0);
                    acc[mtl][nt] = __builtin_amdgcn_mfma_f32_16x16x32_f16(ah, bl[nt], acc[mtl][nt], 0, 0, 0);
                    acc[mtl][nt] = __builtin_amdgcn_mfma_f32_16x16x32_f16(al, bh[nt], acc[mtl][nt], 0, 0, 0);
                }
            }
        }
    }

    float bi[4];
#pragma unroll
    for (int nt = 0; nt < 4; ++nt) bi[nt] = bias[nt * 16 + l15];

#pragma unroll
    for (int mtl = 0; mtl < 2; ++mtl) {
        if (mtl == 1 && w >= 2) continue;
        int t = w + 4 * mtl;
#pragma unroll
        for (int nt = 0; nt < 4; ++nt) {
#pragma unroll
            for (int r = 0; r < 4; ++r) {
                int lp = t * 16 + lg * 4 + r;
                int p = r0 * 24 + lp;
                int oc = nt * 16 + l15;
                float v = acc[mtl][nt][r] + bi[nt];
                if (MODE) {
                    size_t ridx = (size_t)b * 36864 + (size_t)p * 64 + oc;
                    v += (float)resh[ridx] + (float)resl[ridx];
                }
                v = fmaxf(v, 0.f);
                f16 h = (f16)v;
                f16 lo = (f16)(v - (float)h);
                size_t oidx = OUTT ? ((size_t)b * 36864 + (size_t)oc * 576 + p)
                                   : ((size_t)b * 36864 + (size_t)p * 64 + oc);
                outh[oidx] = h;
                outl[oidx] = lo;
            }
        }
    }
}

// ---------------------------------------------------------------------------
// FC via f16-split MFMA (unchanged, verified)
// ---------------------------------------------------------------------------
#define FC_KSPLIT 32

__global__ __launch_bounds__(256) void fc_mfma(
    const f16* __restrict__ Ath, const f16* __restrict__ Atl,
    const float* __restrict__ Bw, float* __restrict__ part)
{
    __shared__ f16 As[2][128 * 40];
    __shared__ f16 Bs[2][16 * 40];
    const int nt = blockIdx.x;
    const int ks = blockIdx.y;
    const int tid = threadIdx.x;
    const int w = tid >> 6, l = tid & 63;
    const int l15 = l & 15, lg = l >> 4;
    const int k0b = ks * 1152;

    f32x4 acc[2];
    acc[0] = (f32x4){0.f, 0.f, 0.f, 0.f};
    acc[1] = (f32x4){0.f, 0.f, 0.f, 0.f};

    const int bn = tid >> 4, bkl = (tid & 15) * 2;
#pragma unroll 1
    for (int st = 0; st < 36; ++st) {
        int k0 = k0b + st * 32;
        __syncthreads();
#pragma unroll
        for (int i = 0; i < 4; ++i) {
            int ch = tid + i * 256;
            int arr = ch >= 512; int c2 = ch - arr * 512;
            int m = c2 >> 2, slot = c2 & 3;
            const f16* src = (arr ? Atl : Ath) + (size_t)m * 36864 + k0 + slot * 8;
            *(uint4*)(void*)&As[arr][m * 40 + slot * 8] = *(const uint4*)(const void*)src;
        }
        {
            float2 f2 = *(const float2*)&Bw[(size_t)(nt * 16 + bn) * 36864 + k0 + bkl];
            f16 h0 = (f16)f2.x, h1 = (f16)f2.y;
            Bs[0][bn * 40 + bkl] = h0;     Bs[0][bn * 40 + bkl + 1] = h1;
            Bs[1][bn * 40 + bkl] = (f16)(f2.x - (float)h0);
            Bs[1][bn * 40 + bkl + 1] = (f16)(f2.y - (float)h1);
        }
        __syncthreads();
        f16x8 bh = *(const f16x8*)(const void*)&Bs[0][l15 * 40 + lg * 8];
        f16x8 bl = *(const f16x8*)(const void*)&Bs[1][l15 * 40 + lg * 8];
#pragma unroll
        for (int mtl = 0; mtl < 2; ++mtl) {
            int m = w * 32 + mtl * 16 + l15;
            f16x8 ah = *(const f16x8*)(const void*)&As[0][m * 40 + lg * 8];
            f16x8 al = *(const f16x8*)(const void*)&As[1][m * 40 + lg * 8];
            acc[mtl] = __builtin_amdgcn_mfma_f32_16x16x32_f16(ah, bh, acc[mtl], 0, 0, 0);
            acc[mtl] = __builtin_amdgcn_mfma_f32_16x16x32_f16(ah, bl, acc[mtl], 0, 0, 0);
            acc[mtl] = __builtin_amdgcn_mfma_f32_16x16x32_f16(al, bh, acc[mtl], 0, 0, 0);
        }
    }
#pragma unroll
    for (int mtl = 0; mtl < 2; ++mtl)
#pragma unroll
        for (int r = 0; r < 4; ++r) {
            int m = w * 32 + mtl * 16 + lg * 4 + r;
            int n = nt * 16 + l15;
            part[((size_t)ks * 128 + m) * 144 + n] = acc[mtl][r];
        }
}

__global__ __launch_bounds__(256) void fc_reduce(
    const float* __restrict__ part, const float* __restrict__ bias,
    float* __restrict__ costs)
{
    int idx = blockIdx.x * 256 + threadIdx.x;
    if (idx >= 128 * 144) return;
    float sum = bias[idx % 144];
    for (int s = 0; s < FC_KSPLIT; ++s) sum += part[(size_t)s * (128 * 144) + idx];
    costs[idx] = sum;
}

// ---------------------------------------------------------------------------
// Bellman-Ford + backtrack: R9 structure + EXACT fixed-point early exit.
// Relaxation is monotone non-increasing; once nothing changes, all remaining
// reference iterations are identity (bit-exact skip). Backtrack breaks once
// (0,0) is masked (reference iterations after that only re-set mask[0,0]).
// Worst case (no convergence): identical to the proven 53 us kernel.
// ---------------------------------------------------------------------------
__global__ __launch_bounds__(192) void shortest_path(
    const float* __restrict__ costs, float* __restrict__ out)
{
    __shared__ float dA[144], dB[144], cs[144], mask[144];
    const int b = blockIdx.x, tid = threadIdx.x;
    if (tid < 144) {
        float c = costs[b * 144 + tid];
        cs[tid] = c;
        dA[tid] = (tid == 0) ? c : BIGF;
        mask[tid] = 0.f;
    }
    __syncthreads();
    float* cur = dA; float* nxt = dB;
    for (int it = 0; it < 144; ++it) {
        int changed = 0;
        if (tid < 144) {
            int i = tid / 12, j = tid % 12;
            float up = (i > 0)  ? cur[tid - 12] : BIGF;
            float dn = (i < 11) ? cur[tid + 12] : BIGF;
            float lf = (j > 0)  ? cur[tid - 1]  : BIGF;
            float rt = (j < 11) ? cur[tid + 1]  : BIGF;
            float nb = fminf(fminf(up, dn), fminf(lf, rt));
            float d0 = cur[tid];
            float d1 = fminf(d0, nb + cs[tid]);
            nxt[tid] = d1;
            changed = (d1 != d0);
        }
        int nch = __syncthreads_count(changed);
        float* tp = cur; cur = nxt; nxt = tp;
        if (nch == 0) break;      // fixed point: remaining ref iters are no-ops
    }
    if (tid == 0) {
        int i = 11, j = 11;
        const int di[4] = {-1, 1, 0, 0};
        const int dj[4] = {0, 0, -1, 1};
        for (int it = 0; it < 144; ++it) {
            mask[i * 12 + j] = 1.f;
            if (i == 0 && j == 0) break;   // ref iters after this only re-set (0,0)
            float vals[4];
#pragma unroll
            for (int k = 0; k < 4; ++k) {
                int ni = i + di[k], nj = j + dj[k];
                bool valid = (ni >= 0) && (ni < 12) && (nj >= 0) && (nj < 12);
                vals[k] = valid ? cur[ni * 12 + nj] : BIGF;
            }
            float best = vals[0]; int kb = 0;
#pragma unroll
            for (int k = 1; k < 4; ++k)
                if (vals[k] < best) { best = vals[k]; kb = k; }   // first-min
            i += di[kb]; j += dj[kb];
        }
    }
    __syncthreads();
    if (tid < 144) out[b * 144 + tid] = mask[tid];
}

// ---------------------------------------------------------------------------
extern "C" void kernel_launch(void* const* d_in, const int* in_sizes, int n_in,
                              void* d_out, int out_size, void* d_ws, size_t ws_size,
                              hipStream_t stream) {
    const float* x    = (const float*)d_in[0];
    const float* c1w  = (const float*)d_in[1];
    const float* bn1g = (const float*)d_in[2];
    const float* bn1b = (const float*)d_in[3];
    const float* bn1m = (const float*)d_in[4];
    const float* bn1v = (const float*)d_in[5];
    const float* blkw = (const float*)d_in[6];
    const float* blkg = (const float*)d_in[7];
    const float* blkb = (const float*)d_in[8];
    const float* blkm = (const float*)d_in[9];
    const float* blkv = (const float*)d_in[10];
    const float* fcw  = (const float*)d_in[11];
    const float* fcb  = (const float*)d_in[12];
    float* out = (float*)d_out;
    char* ws = (char*)d_ws;

    const size_t APL = 9437184;            // 128*36864 halves * 2B
    f16* a0h = (f16*)(ws);
    f16* a0l = (f16*)(ws + APL);
    f16* a1h = (f16*)(ws + 2 * APL);
    f16* a1l = (f16*)(ws + 3 * APL);
    f16* a2h = (f16*)(ws + 4 * APL);
    f16* a2l = (f16*)(ws + 5 * APL);
    float* costs = (float*)(ws + 6 * APL);                       // 73728 B
    float* part  = (float*)(ws + 6 * APL + 73728);               // 2359296 B
    f16*   wB    = (f16*)  (ws + 6 * APL + 73728 + 2359296);     // 589824 B
    float* b3    = (float*)(ws + 6 * APL + 73728 + 2359296 + 589824);       // 1024 B
    float* b1    = (float*)(ws + 6 * APL + 73728 + 2359296 + 589824 + 1024);// 256 B
    f16*   wB1   = (f16*)  (ws + 6 * APL + 73728 + 2359296 + 589824 + 1280);// 57344 B

    prepack<<<dim3(690), dim3(256), 0, stream>>>(
        c1w, bn1g, bn1b, bn1m, bn1v, blkw, blkg, blkb, blkm, blkv,
        wB, wB1, b3, b1);

    conv1_mfma<<<dim3(12, 128), dim3(256), 0, stream>>>(x, wB1, b1, a0h, a0l);

    conv3_mfma<0, 0><<<dim3(6, 128), dim3(256), 0, stream>>>(
        a0h, a0l, wB + 0 * 73728, b3 + 0,   nullptr, nullptr, a1h, a1l);
    conv3_mfma<1, 0><<<dim3(6, 128), dim3(256), 0, stream>>>(
        a1h, a1l, wB + 1 * 73728, b3 + 64,  a0h, a0l, a2h, a2l);
    conv3_mfma<0, 0><<<dim3(6, 128), dim3(256), 0, stream>>>(
        a2h, a2l, wB + 2 * 73728, b3 + 128, nullptr, nullptr, a1h, a1l);
    conv3_mfma<1, 1><<<dim3(6, 128), dim3(256), 0, stream>>>(
        a1h, a1l, wB + 3 * 73728, b3 + 192, a2h, a2l, a0h, a0l);  // NCHW-T out

    fc_mfma<<<dim3(9, FC_KSPLIT), dim3(256), 0, stream>>>(a0h, a0l, fcw, part);
    fc_reduce<<<dim3(72), dim3(256), 0, stream>>>(part, fcb, costs);
    shortest_path<<<dim3(128), dim3(192), 0, stream>>>(costs, out);
}

// Round 17
// 222.513 us; speedup vs baseline: 1.2289x; 1.2289x over previous
//
#include <hip/hip_runtime.h>
#include <math.h>

#define BIGF 1e10f
#define EPSF 1e-5f

typedef _Float16 f16;
typedef f16 f16x8 __attribute__((ext_vector_type(8)));
typedef float f32x4 __attribute__((ext_vector_type(4)));

static __device__ __forceinline__ f16x8 mk8(uint a, uint b, uint c, uint d) {
    union { uint u[4]; f16x8 v; } t;
    t.u[0] = a; t.u[1] = b; t.u[2] = c; t.u[3] = d;
    return t.v;
}

// ---------------------------------------------------------------------------
// Prepack (unchanged, verified)
// ---------------------------------------------------------------------------
__global__ __launch_bounds__(256) void prepack(
    const float* __restrict__ c1w,
    const float* __restrict__ bn1g, const float* __restrict__ bn1b,
    const float* __restrict__ bn1m, const float* __restrict__ bn1v,
    const float* __restrict__ blkw,
    const float* __restrict__ blkg, const float* __restrict__ blkb,
    const float* __restrict__ blkm, const float* __restrict__ blkv,
    f16* __restrict__ wB, f16* __restrict__ wB1,
    float* __restrict__ b3, float* __restrict__ b1)
{
    int idx = blockIdx.x * 256 + threadIdx.x;
    if (idx < 147456) {                    // conv3 weight frags
        int pos = idx;
        int j    = pos & 7;
        int lane = (pos >> 3) & 63;
        int rest = pos >> 9;               // (((layer*9+tap)*4+nt)*2+kf)
        int kf   = rest & 1;
        int r2   = rest >> 1;
        int ntl  = r2 & 3;
        int r3   = r2 >> 2;
        int tap  = r3 % 9;
        int layer= r3 / 9;
        int ic = kf * 32 + (lane >> 4) * 8 + j;
        int oc = ntl * 16 + (lane & 15);
        float s = blkg[layer * 64 + oc] * rsqrtf(blkv[layer * 64 + oc] + EPSF);
        float wv = blkw[(((size_t)layer * 64 + oc) * 64 + ic) * 9 + tap] * s;
        f16 h = (f16)wv;
        f16 lo = (f16)(wv - (float)h);
        int low9 = pos & 511;
        wB[(size_t)rest * 1024 + low9]       = h;
        wB[(size_t)rest * 1024 + 512 + low9] = lo;
    }
    int q = idx - 147456;
    if (q >= 0 && q < 28672) {             // conv1 frags
        int j = q & 7, lane = (q >> 3) & 63, rest = q >> 9;  // ((kh*4+nt)*2+hl)
        int hl = rest & 1, nt = (rest >> 1) & 3, kh = rest >> 3;
        int oc = nt * 16 + (lane & 15), lgq = lane >> 4;
        float v = 0.f;
        if (lgq < 3 && j < 7) {
            float s = bn1g[oc] * rsqrtf(bn1v[oc] + EPSF);
            v = c1w[((oc * 3 + lgq) * 7 + kh) * 7 + j] * s;
        }
        f16 h = (f16)v;
        wB1[q] = hl ? (f16)(v - (float)h) : h;
    }
    int k = idx - 147456 - 28672;
    if (k >= 0 && k < 256) {
        float s = blkg[k] * rsqrtf(blkv[k] + EPSF);
        b3[k] = blkb[k] - blkm[k] * s;
    }
    int l = idx - 147456 - 28672 - 256;
    if (l >= 0 && l < 64) {
        float s = bn1g[l] * rsqrtf(bn1v[l] + EPSF);
        b1[l] = bn1b[l] - bn1m[l] * s;
    }
}

// ---------------------------------------------------------------------------
// conv1 7x7 s2 p3 + foldedBN + ReLU + maxpool via f16-split MFMA.
// (R9-verified, unchanged)
// ---------------------------------------------------------------------------
__global__ __launch_bounds__(256) void conv1_mfma(
    const float* __restrict__ x, const f16* __restrict__ wB1,
    const float* __restrict__ bias,
    f16* __restrict__ outh, f16* __restrict__ outl)
{
    __shared__ char lds[18720];
    const int g = blockIdx.x, b = blockIdx.y;
    const int tid = threadIdx.x;
    const int w = tid >> 6, l = tid & 63;
    const int l15 = l & 15, lg = l >> 4;

    for (int i = tid; i < 4680; i += 256) ((uint*)lds)[i] = 0u;
    __syncthreads();
    const int ir0 = 8 * g - 5;
    const float* xb = x + (size_t)b * 27648;
    for (int u = tid; u < 2205; u += 256) {
        int cu = 1 + (u % 49);
        int rr = (u / 49) % 15;
        int ic = u / 735;
        int ir = ir0 + rr;
        uint pk_h = 0u, pk_l = 0u;
        if ((unsigned)ir < 96u) {
            int c0i = 2 * cu - 3, c1i = 2 * cu - 2;
            const float* rowp = xb + ic * 9216 + ir * 96;
            float v0 = (c0i >= 0) ? rowp[c0i] : 0.f;
            float v1 = (c1i <= 95) ? rowp[c1i] : 0.f;
            f16 h0 = (f16)v0; f16 lo0 = (f16)(v0 - (float)h0);
            f16 h1 = (f16)v1; f16 lo1 = (f16)(v1 - (float)h1);
            union { f16 f[2]; uint u32; } ph, pl;
            ph.f[0] = h0;  ph.f[1] = h1;  pk_h = ph.u32;
            pl.f[0] = lo0; pl.f[1] = lo1; pk_l = pl.u32;
        }
        int off = ic * 3120 + rr * 208 + 4 * cu;
        *(uint*)(lds + off) = pk_h;
        *(uint*)(lds + 9360 + off) = pk_l;
    }
    __syncthreads();

    f32x4 acc[4][4];
#pragma unroll
    for (int k = 0; k < 4; ++k)
#pragma unroll
        for (int nt = 0; nt < 4; ++nt) acc[k][nt] = (f32x4){0.f, 0.f, 0.f, 0.f};

    const int icB = (lg >= 3 ? 0 : lg) * 3120;
    const char* hbase = lds + icB;
    const char* lbase = lds + 9360 + icB;
    const f16* wq = wB1 + (size_t)l * 8;

    int rowoff[4], aoff[4];
#pragma unroll
    for (int k = 0; k < 4; ++k) {
        int t = w + 4 * k;
        int tt = (t < 15) ? t : 0;
        rowoff[k] = tt / 3;
        aoff[k] = 4 * ((tt % 3) * 16 + l15);
    }

#pragma unroll 1
    for (int kh = 0; kh < 7; ++kh) {
        const f16* wk = wq + kh * 4096;
        f16x8 bq[4];
#pragma unroll
        for (int nt = 0; nt < 4; ++nt)
            bq[nt] = *(const f16x8*)(const void*)(wk + nt * 1024);
#pragma unroll
        for (int k = 0; k < 4; ++k) {
            if (w + 4 * k < 15) {
                int ro = (2 * rowoff[k] + kh) * 208 + aoff[k];
                const uint* ph = (const uint*)(hbase + ro);
                const uint* pl = (const uint*)(lbase + ro);
                f16x8 ah = mk8(ph[0], ph[1], ph[2], ph[3]);
                f16x8 al = mk8(pl[0], pl[1], pl[2], pl[3]);
#pragma unroll
                for (int nt = 0; nt < 4; ++nt) {
                    acc[k][nt] = __builtin_amdgcn_mfma_f32_16x16x32_f16(ah, bq[nt], acc[k][nt], 0, 0, 0);
                    acc[k][nt] = __builtin_amdgcn_mfma_f32_16x16x32_f16(al, bq[nt], acc[k][nt], 0, 0, 0);
                }
            }
        }
#pragma unroll
        for (int nt = 0; nt < 4; ++nt)
            bq[nt] = *(const f16x8*)(const void*)(wk + nt * 1024 + 512);
#pragma unroll
        for (int k = 0; k < 4; ++k) {
            if (w + 4 * k < 15) {
                int ro = (2 * rowoff[k] + kh) * 208 + aoff[k];
                const uint* ph = (const uint*)(hbase + ro);
                f16x8 ah = mk8(ph[0], ph[1], ph[2], ph[3]);
#pragma unroll
                for (int nt = 0; nt < 4; ++nt)
                    acc[k][nt] = __builtin_amdgcn_mfma_f32_16x16x32_f16(ah, bq[nt], acc[k][nt], 0, 0, 0);
            }
        }
    }

    __syncthreads();
    float* pbuf = (float*)(void*)lds;
#pragma unroll
    for (int og = 0; og < 4; ++og) {
        float bi = bias[og * 16 + l15];
#pragma unroll
        for (int k = 0; k < 4; ++k) {
            int t = w + 4 * k;
            if (t < 15) {
                int lr = t / 3;
                int c0 = (t % 3) * 16;
#pragma unroll
                for (int r = 0; r < 4; ++r) {
                    int col = c0 + lg * 4 + r;
                    pbuf[(lr * 48 + col) * 17 + l15] = fmaxf(acc[k][og][r] + bi, 0.f);
                }
            }
        }
        __syncthreads();
#pragma unroll
        for (int it = 0; it < 3; ++it) {
            int idx = tid + it * 256;
            int oc = idx & 15, p2 = idx >> 4;
            int pc2 = p2 % 24, pr2 = p2 / 24;
            float m = -INFINITY;
#pragma unroll
            for (int kr = 0; kr < 3; ++kr) {
                int lr = 2 * pr2 + kr;
                if (g == 0 && lr == 0) continue;
#pragma unroll
                for (int kc = 0; kc < 3; ++kc) {
                    int cc = 2 * pc2 - 1 + kc;
                    if ((unsigned)cc < 48u)
                        m = fmaxf(m, pbuf[(lr * 48 + cc) * 17 + oc]);
                }
            }
            f16 h = (f16)m;
            f16 lo = (f16)(m - (float)h);
            size_t off = (size_t)b * 36864 +
                         (size_t)((2 * g + pr2) * 24 + pc2) * 64 + og * 16 + oc;
            outh[off] = h;
            outl[off] = lo;
        }
        __syncthreads();
    }
}

// ---------------------------------------------------------------------------
// conv3x3 s1 p1 (64->64) + foldedBN (+res) + ReLU via f16-split MFMA, v2:
// 4-row blocks, grid (6,128) = 3 blocks/CU. (R15-verified)
// ---------------------------------------------------------------------------
template<int MODE, int OUTT>
__global__ __launch_bounds__(256) void conv3_mfma(
    const f16* __restrict__ inh, const f16* __restrict__ inl,
    const f16* __restrict__ wB,      // this layer's frag base (73728 halves)
    const float* __restrict__ bias,  // folded [64]
    const f16* __restrict__ resh, const f16* __restrict__ resl,
    f16* __restrict__ outh, f16* __restrict__ outl)
{
    __shared__ f16 lh[6 * 26 * 64];
    __shared__ f16 ll[6 * 26 * 64];
    const int r0 = blockIdx.x * 4;
    const int b  = blockIdx.y;
    const int tid = threadIdx.x;
    const int w = tid >> 6, l = tid & 63;
    const int l15 = l & 15, lg = l >> 4;

    if (tid < 192) {
        int arr = tid >= 96; int c2 = tid - arr * 96;
        int slot = c2 & 7; int pb = c2 >> 3;
        int lr = pb >> 1; int pc = (pb & 1) ? 25 : 0;
        int pix = lr * 26 + pc;
        int off = (pix * 128 + slot * 16) ^ ((pix & 7) << 4);
        *(uint4*)((arr ? (char*)ll : (char*)lh) + off) = make_uint4(0, 0, 0, 0);
    }
#pragma unroll
    for (int i = 0; i < 9; ++i) {
        int ch = tid + i * 256;
        int arr = ch >= 1152; int c2 = ch - arr * 1152;
        int slot = c2 & 7; int pix24 = c2 >> 3;
        int lr = pix24 / 24, pc = pix24 % 24;
        int ir = r0 - 1 + lr;
        uint4 v = make_uint4(0, 0, 0, 0);
        if ((unsigned)ir < 24u) {
            const f16* src = (arr ? inl : inh) +
                (((size_t)b * 576 + ir * 24 + pc) << 6) + slot * 8;
            v = *(const uint4*)(const void*)src;
        }
        int pix = lr * 26 + pc + 1;
        int off = (pix * 128 + slot * 16) ^ ((pix & 7) << 4);
        *(uint4*)((arr ? (char*)ll : (char*)lh) + off) = v;
    }

    int pr_[2], pc_[2];
#pragma unroll
    for (int mtl = 0; mtl < 2; ++mtl) {
        int t = w + 4 * mtl;
        int tt = (t < 6) ? t : 0;
        int lp = tt * 16 + l15;
        pr_[mtl] = lp / 24; pc_[mtl] = lp % 24;
    }

    f32x4 acc[2][4];
#pragma unroll
    for (int m = 0; m < 2; ++m)
#pragma unroll
        for (int n = 0; n < 4; ++n) acc[m][n] = (f32x4){0.f, 0.f, 0.f, 0.f};

    __syncthreads();

#pragma unroll 1
    for (int tap = 0; tap < 9; ++tap) {
        int dr = tap / 3, dc = tap % 3;
#pragma unroll
        for (int kf = 0; kf < 2; ++kf) {
            const f16* wb = wB + (size_t)tap * 8192 + (size_t)kf * 1024 + (size_t)l * 8;
            f16x8 bh[4], bl[4];
#pragma unroll
            for (int nt = 0; nt < 4; ++nt) {
                bh[nt] = *(const f16x8*)(const void*)(wb + nt * 2048);
                bl[nt] = *(const f16x8*)(const void*)(wb + nt * 2048 + 512);
            }
#pragma unroll
            for (int mtl = 0; mtl < 2; ++mtl) {
                if (mtl == 1 && w >= 2) continue;
                int pix = (pr_[mtl] + dr) * 26 + (pc_[mtl] + dc);
                int off = (pix * 128 + kf * 64 + lg * 16) ^ ((pix & 7) << 4);
                f16x8 ah = *(const f16x8*)((const char*)lh + off);
                f16x8 al = *(const f16x8*)((const char*)ll + off);
#pragma unroll
                for (int nt = 0; nt < 4; ++nt) {
                    acc[mtl][nt] = __builtin_amdgcn_mfma_f32_16x16x32_f16(ah, bh[nt], acc[mtl][nt], 0, 0, 0);
                    acc[mtl][nt] = __builtin_amdgcn_mfma_f32_16x16x32_f16(ah, bl[nt], acc[mtl][nt], 0, 0, 0);
                    acc[mtl][nt] = __builtin_amdgcn_mfma_f32_16x16x32_f16(al, bh[nt], acc[mtl][nt], 0, 0, 0);
                }
            }
        }
    }

    float bi[4];
#pragma unroll
    for (int nt = 0; nt < 4; ++nt) bi[nt] = bias[nt * 16 + l15];

#pragma unroll
    for (int mtl = 0; mtl < 2; ++mtl) {
        if (mtl == 1 && w >= 2) continue;
        int t = w + 4 * mtl;
#pragma unroll
        for (int nt = 0; nt < 4; ++nt) {
#pragma unroll
            for (int r = 0; r < 4; ++r) {
                int lp = t * 16 + lg * 4 + r;
                int p = r0 * 24 + lp;
                int oc = nt * 16 + l15;
                float v = acc[mtl][nt][r] + bi[nt];
                if (MODE) {
                    size_t ridx = (size_t)b * 36864 + (size_t)p * 64 + oc;
                    v += (float)resh[ridx] + (float)resl[ridx];
                }
                v = fmaxf(v, 0.f);
                f16 h = (f16)v;
                f16 lo = (f16)(v - (float)h);
                size_t oidx = OUTT ? ((size_t)b * 36864 + (size_t)oc * 576 + p)
                                   : ((size_t)b * 36864 + (size_t)p * 64 + oc);
                outh[oidx] = h;
                outl[oidx] = lo;
            }
        }
    }
}

// ---------------------------------------------------------------------------
// FC via f16-split MFMA (unchanged, verified)
// ---------------------------------------------------------------------------
#define FC_KSPLIT 32

__global__ __launch_bounds__(256) void fc_mfma(
    const f16* __restrict__ Ath, const f16* __restrict__ Atl,
    const float* __restrict__ Bw, float* __restrict__ part)
{
    __shared__ f16 As[2][128 * 40];
    __shared__ f16 Bs[2][16 * 40];
    const int nt = blockIdx.x;
    const int ks = blockIdx.y;
    const int tid = threadIdx.x;
    const int w = tid >> 6, l = tid & 63;
    const int l15 = l & 15, lg = l >> 4;
    const int k0b = ks * 1152;

    f32x4 acc[2];
    acc[0] = (f32x4){0.f, 0.f, 0.f, 0.f};
    acc[1] = (f32x4){0.f, 0.f, 0.f, 0.f};

    const int bn = tid >> 4, bkl = (tid & 15) * 2;
#pragma unroll 1
    for (int st = 0; st < 36; ++st) {
        int k0 = k0b + st * 32;
        __syncthreads();
#pragma unroll
        for (int i = 0; i < 4; ++i) {
            int ch = tid + i * 256;
            int arr = ch >= 512; int c2 = ch - arr * 512;
            int m = c2 >> 2, slot = c2 & 3;
            const f16* src = (arr ? Atl : Ath) + (size_t)m * 36864 + k0 + slot * 8;
            *(uint4*)(void*)&As[arr][m * 40 + slot * 8] = *(const uint4*)(const void*)src;
        }
        {
            float2 f2 = *(const float2*)&Bw[(size_t)(nt * 16 + bn) * 36864 + k0 + bkl];
            f16 h0 = (f16)f2.x, h1 = (f16)f2.y;
            Bs[0][bn * 40 + bkl] = h0;     Bs[0][bn * 40 + bkl + 1] = h1;
            Bs[1][bn * 40 + bkl] = (f16)(f2.x - (float)h0);
            Bs[1][bn * 40 + bkl + 1] = (f16)(f2.y - (float)h1);
        }
        __syncthreads();
        f16x8 bh = *(const f16x8*)(const void*)&Bs[0][l15 * 40 + lg * 8];
        f16x8 bl = *(const f16x8*)(const void*)&Bs[1][l15 * 40 + lg * 8];
#pragma unroll
        for (int mtl = 0; mtl < 2; ++mtl) {
            int m = w * 32 + mtl * 16 + l15;
            f16x8 ah = *(const f16x8*)(const void*)&As[0][m * 40 + lg * 8];
            f16x8 al = *(const f16x8*)(const void*)&As[1][m * 40 + lg * 8];
            acc[mtl] = __builtin_amdgcn_mfma_f32_16x16x32_f16(ah, bh, acc[mtl], 0, 0, 0);
            acc[mtl] = __builtin_amdgcn_mfma_f32_16x16x32_f16(ah, bl, acc[mtl], 0, 0, 0);
            acc[mtl] = __builtin_amdgcn_mfma_f32_16x16x32_f16(al, bh, acc[mtl], 0, 0, 0);
        }
    }
#pragma unroll
    for (int mtl = 0; mtl < 2; ++mtl)
#pragma unroll
        for (int r = 0; r < 4; ++r) {
            int m = w * 32 + mtl * 16 + lg * 4 + r;
            int n = nt * 16 + l15;
            part[((size_t)ks * 128 + m) * 144 + n] = acc[mtl][r];
        }
}

__global__ __launch_bounds__(256) void fc_reduce(
    const float* __restrict__ part, const float* __restrict__ bias,
    float* __restrict__ costs)
{
    int idx = blockIdx.x * 256 + threadIdx.x;
    if (idx >= 128 * 144) return;
    float sum = bias[idx % 144];
    for (int s = 0; s < FC_KSPLIT; ++s) sum += part[(size_t)s * (128 * 144) + idx];
    costs[idx] = sum;
}

// ---------------------------------------------------------------------------
// Bellman-Ford v7: fused 2-step relaxation, 72 barriers for 144 reference
// iterations (bit-exact: first-relax values recomputed locally with the
// reference's exact fp op order; 2-wide BIG pads make all reads branch-free;
// garbage-value discrepancies at 1e10 scale provably cannot reach the final
// dist since every cell's true path sum is ~1e5 smaller). Plain barriers
// (R16 showed __syncthreads_count costs +260cy/iter). Backtrack: padded
// reads, break at (0,0) (pure win).
// ---------------------------------------------------------------------------
__global__ __launch_bounds__(192) void shortest_path(
    const float* __restrict__ costs, float* __restrict__ out)
{
    __shared__ float dP[2][256];   // [16][16], 2-wide BIG border
    __shared__ float cP[256];      // padded costs, border BIG
    __shared__ float mask[144];
    const int b = blockIdx.x, tid = threadIdx.x;

    if (tid < 128) {
        dP[0][tid] = BIGF; dP[0][tid + 128] = BIGF;
        dP[1][tid] = BIGF; dP[1][tid + 128] = BIGF;
        cP[tid] = BIGF;    cP[tid + 128] = BIGF;
    }
    if (tid < 144) mask[tid] = 0.f;
    __syncthreads();

    const int i = tid / 12, j = tid % 12;
    const int p = (i + 2) * 16 + (j + 2);
    if (tid < 144) {
        float c = costs[b * 144 + tid];
        cP[p] = c;
        if (tid == 0) dP[0][p] = c;     // dist[0,0] = costs[0,0]
    }
    __syncthreads();

    float cS = 0.f, cU = 0.f, cD = 0.f, cL = 0.f, cR = 0.f;
    if (tid < 144) {
        cS = cP[p];
        cU = cP[p - 16]; cD = cP[p + 16];
        cL = cP[p - 1];  cR = cP[p + 1];
    }

    int cur = 0;
#pragma unroll 1
    for (int it = 0; it < 72; ++it) {       // 72 x 2 = 144 reference iters
        if (tid < 144) {
            const float* cb = dP[cur];
            float dS = cb[p];
            float dU = cb[p - 16], dD = cb[p + 16], dL = cb[p - 1],  dR = cb[p + 1];
            float dUU = cb[p - 32], dDD = cb[p + 32], dLL = cb[p - 2], dRR = cb[p + 2];
            float dUL = cb[p - 17], dUR = cb[p - 15], dDL = cb[p + 15], dDR = cb[p + 17];
            // first relax (reference op order) for self + 4 neighbors
            float ndU = fminf(dU, fminf(fminf(dUU, dS), fminf(dUL, dUR)) + cU);
            float ndD = fminf(dD, fminf(fminf(dS, dDD), fminf(dDL, dDR)) + cD);
            float ndL = fminf(dL, fminf(fminf(dUL, dDL), fminf(dLL, dS)) + cL);
            float ndR = fminf(dR, fminf(fminf(dUR, dDR), fminf(dS, dRR)) + cR);
            float ndS = fminf(dS, fminf(fminf(dU, dD), fminf(dL, dR)) + cS);
            // second relax
            float d2 = fminf(ndS, fminf(fminf(ndU, ndD), fminf(ndL, ndR)) + cS);
            dP[cur ^ 1][p] = d2;
        }
        __syncthreads();
        cur ^= 1;
    }

    if (tid == 0) {
        const float* fb = dP[cur];
        int pi = 11, pj = 11;
#pragma unroll 1
        for (int it = 0; it < 144; ++it) {
            mask[pi * 12 + pj] = 1.f;
            if (pi == 0 && pj == 0) break;   // remaining ref iters only re-set (0,0)
            int pp = (pi + 2) * 16 + (pj + 2);
            float vu = fb[pp - 16];          // pads give BIG for out-of-grid
            float vd = fb[pp + 16];
            float vl = fb[pp - 1];
            float vr = fb[pp + 1];
            float best = vu; int kb = 0;     // first-min: up, down, left, right
            if (vd < best) { best = vd; kb = 1; }
            if (vl < best) { best = vl; kb = 2; }
            if (vr < best) { best = vr; kb = 3; }
            pi += (kb == 0) ? -1 : (kb == 1) ? 1 : 0;
            pj += (kb == 2) ? -1 : (kb == 3) ? 1 : 0;
        }
    }
    __syncthreads();
    if (tid < 144) out[b * 144 + tid] = mask[tid];
}

// ---------------------------------------------------------------------------
extern "C" void kernel_launch(void* const* d_in, const int* in_sizes, int n_in,
                              void* d_out, int out_size, void* d_ws, size_t ws_size,
                              hipStream_t stream) {
    const float* x    = (const float*)d_in[0];
    const float* c1w  = (const float*)d_in[1];
    const float* bn1g = (const float*)d_in[2];
    const float* bn1b = (const float*)d_in[3];
    const float* bn1m = (const float*)d_in[4];
    const float* bn1v = (const float*)d_in[5];
    const float* blkw = (const float*)d_in[6];
    const float* blkg = (const float*)d_in[7];
    const float* blkb = (const float*)d_in[8];
    const float* blkm = (const float*)d_in[9];
    const float* blkv = (const float*)d_in[10];
    const float* fcw  = (const float*)d_in[11];
    const float* fcb  = (const float*)d_in[12];
    float* out = (float*)d_out;
    char* ws = (char*)d_ws;

    const size_t APL = 9437184;            // 128*36864 halves * 2B
    f16* a0h = (f16*)(ws);
    f16* a0l = (f16*)(ws + APL);
    f16* a1h = (f16*)(ws + 2 * APL);
    f16* a1l = (f16*)(ws + 3 * APL);
    f16* a2h = (f16*)(ws + 4 * APL);
    f16* a2l = (f16*)(ws + 5 * APL);
    float* costs = (float*)(ws + 6 * APL);                       // 73728 B
    float* part  = (float*)(ws + 6 * APL + 73728);               // 2359296 B
    f16*   wB    = (f16*)  (ws + 6 * APL + 73728 + 2359296);     // 589824 B
    float* b3    = (float*)(ws + 6 * APL + 73728 + 2359296 + 589824);       // 1024 B
    float* b1    = (float*)(ws + 6 * APL + 73728 + 2359296 + 589824 + 1024);// 256 B
    f16*   wB1   = (f16*)  (ws + 6 * APL + 73728 + 2359296 + 589824 + 1280);// 57344 B

    prepack<<<dim3(690), dim3(256), 0, stream>>>(
        c1w, bn1g, bn1b, bn1m, bn1v, blkw, blkg, blkb, blkm, blkv,
        wB, wB1, b3, b1);

    conv1_mfma<<<dim3(12, 128), dim3(256), 0, stream>>>(x, wB1, b1, a0h, a0l);

    conv3_mfma<0, 0><<<dim3(6, 128), dim3(256), 0, stream>>>(
        a0h, a0l, wB + 0 * 73728, b3 + 0,   nullptr, nullptr, a1h, a1l);
    conv3_mfma<1, 0><<<dim3(6, 128), dim3(256), 0, stream>>>(
        a1h, a1l, wB + 1 * 73728, b3 + 64,  a0h, a0l, a2h, a2l);
    conv3_mfma<0, 0><<<dim3(6, 128), dim3(256), 0, stream>>>(
        a2h, a2l, wB + 2 * 73728, b3 + 128, nullptr, nullptr, a1h, a1l);
    conv3_mfma<1, 1><<<dim3(6, 128), dim3(256), 0, stream>>>(
        a1h, a1l, wB + 3 * 73728, b3 + 192, a2h, a2l, a0h, a0l);  // NCHW-T out

    fc_mfma<<<dim3(9, FC_KSPLIT), dim3(256), 0, stream>>>(a0h, a0l, fcw, part);
    fc_reduce<<<dim3(72), dim3(256), 0, stream>>>(part, fcb, costs);
    shortest_path<<<dim3(128), dim3(192), 0, stream>>>(costs, out);
}